// Round 12
// baseline (87.101 us; speedup 1.0000x reference)
//
#include <hip/hip_runtime.h>
#include <hip/hip_bf16.h>

// Problem: B=4, S=128, H=768, OUT*TAG=96
// scores[b,i,j,o] = sum_k relu(head[b,i,k] + tail[b,j,k] + b1[k]) * W2[k,o] + b2[o]
// R11: pair kernel on mfma_f32_32x32x16_f16 — W2 fragment reused across 32 j
//      (LDS bytes/FLOP halved). 2-wave blocks, wave = 2i x 32j, grid 512.
//      R7-proven ring-4 pipeline, counted vmcnt(18), uniform dummy stages.

typedef __bf16 bf16x8 __attribute__((ext_vector_type(8)));
typedef _Float16 f16x8 __attribute__((ext_vector_type(8)));
typedef float f32x4 __attribute__((ext_vector_type(4)));
typedef float f32x16 __attribute__((ext_vector_type(16)));

#define S_   128
#define H_   768
#define K3   2304   // 3*H
#define NOUT 96
#define NIT  36     // K-step-64 iterations

__device__ __forceinline__ unsigned short f2bf(float f) {
    union { __bf16 b; unsigned short u; } c;
    c.b = (__bf16)f;   // RNE
    return c.u;
}

__device__ __forceinline__ unsigned short f2h(float f) {
    union { _Float16 h; unsigned short u; } c;
    c.h = (_Float16)f;
    return c.u;
}

__device__ __forceinline__ void gload_lds16(const unsigned short* g, unsigned short* l) {
    __builtin_amdgcn_global_load_lds(
        (const __attribute__((address_space(1))) void*)g,
        (__attribute__((address_space(3))) void*)l,
        16, 0, 0);
}

// ---------- prep: x fp32 -> bf16 (layout unchanged, [512][768]) ----------
__global__ void k_cvt_x(const float4* __restrict__ x, ushort4* __restrict__ xb) {
    int t = blockIdx.x * 256 + threadIdx.x;   // 98304 threads, exact
    float4 v = x[t];
    ushort4 o;
    o.x = f2bf(v.x); o.y = f2bf(v.y); o.z = f2bf(v.z); o.w = f2bf(v.w);
    xb[t] = o;
}

// ---------- prep: transpose fp32 [R][C] -> bf16 [C][R] (for W1) ----------
__global__ void k_transpose(const float* __restrict__ src, unsigned short* __restrict__ dst,
                            int R, int C, long srcZ, long dstZ) {
    src += (long)blockIdx.z * srcZ;
    dst += (long)blockIdx.z * dstZ;
    __shared__ float tile[32][33];
    int c0 = blockIdx.x * 32, r0 = blockIdx.y * 32;
    int row = threadIdx.x >> 3;          // 0..31
    int c4  = (threadIdx.x & 7) * 4;     // 0..28
    float4 v = *(const float4*)(src + (size_t)(r0 + row) * C + c0 + c4);
    tile[row][c4 + 0] = v.x; tile[row][c4 + 1] = v.y;
    tile[row][c4 + 2] = v.z; tile[row][c4 + 3] = v.w;
    __syncthreads();
    ushort4 o;
    o.x = f2bf(tile[c4 + 0][row]); o.y = f2bf(tile[c4 + 1][row]);
    o.z = f2bf(tile[c4 + 2][row]); o.w = f2bf(tile[c4 + 3][row]);
    *(ushort4*)(dst + (size_t)(c0 + row) * R + r0 + c4) = o;
}

// ---------- prep: pack W2 f32 [2304][96] -> f16 32x32-frag order [144][3][64][8] ----------
// slice s (16 k), og (32 o): lane l elem e = W2[s*16 + (l>>5)*8 + e][og*32 + (l&31)]
__global__ void k_pack_w2(const float* __restrict__ W2,
                          unsigned short* __restrict__ w2f) {
    int t = blockIdx.x * 256 + threadIdx.x;   // 27648 threads exact (108 blocks)
    int l = t & 63, og = (t >> 6) % 3, s = t / 192;
    int k0 = s * 16 + (l >> 5) * 8;
    int o  = og * 32 + (l & 31);
    unsigned short v[8];
#pragma unroll
    for (int e = 0; e < 8; e++)
        v[e] = f2h(W2[(size_t)(k0 + e) * NOUT + o]);
    *(uint4*)(w2f + (size_t)t * 8) = *(const uint4*)v;
}

// ---------- GEMM1: bf16 MFMA, outputs stored as f16 ----------
__global__ __launch_bounds__(256) void k_gemm1(
        const unsigned short* __restrict__ xb,     // [512][768] bf16
        const unsigned short* __restrict__ w1t,    // [4608][768] bf16
        const float* __restrict__ b1,              // [2304]
        unsigned short* __restrict__ headh,        // [512][2304] f16
        unsigned short* __restrict__ tailh) {      // [512][2304] f16
    __shared__ unsigned short As[128 * 32];
    __shared__ unsigned short Bs[128 * 32];
    const int tid = threadIdx.x;
    const int l = tid & 63, w = tid >> 6;
    const int m0 = blockIdx.y * 128;
    const int n0 = blockIdx.x * 128;
    const int wr = (w >> 1) * 64, wc = (w & 1) * 64;
    const int lr = l & 15, lk = (l >> 4) * 8;
    f32x4 acc[4][4] = {};

    for (int kt = 0; kt < H_; kt += 32) {
#pragma unroll
        for (int p = 0; p < 2; ++p) {
            int idx = p * 256 + tid;
            int row = idx >> 2, seg = (idx & 3) * 8;
            gload_lds16(xb  + (size_t)(m0 + row) * H_ + kt + seg, As + idx * 8);
            gload_lds16(w1t + (size_t)(n0 + row) * H_ + kt + seg, Bs + idx * 8);
        }
        asm volatile("s_waitcnt vmcnt(0)" ::: "memory");
        __syncthreads();
        bf16x8 af[4], bfr[4];
#pragma unroll
        for (int i = 0; i < 4; i++) af[i]  = *(const bf16x8*)(As + (wr + i * 16 + lr) * 32 + lk);
#pragma unroll
        for (int j = 0; j < 4; j++) bfr[j] = *(const bf16x8*)(Bs + (wc + j * 16 + lr) * 32 + lk);
#pragma unroll
        for (int i = 0; i < 4; i++)
#pragma unroll
            for (int j = 0; j < 4; j++)
                acc[i][j] = __builtin_amdgcn_mfma_f32_16x16x32_bf16(af[i], bfr[j], acc[i][j], 0, 0, 0);
        __syncthreads();
    }

    const bool tailblk = (n0 >= K3);
    unsigned short* dst = tailblk ? tailh : headh;
    const int nloc = n0 - (tailblk ? K3 : 0);
    const int lv = (l >> 4) * 4;
#pragma unroll
    for (int j = 0; j < 4; j++) {
        int c = nloc + wc + j * 16 + lr;
        float bias = tailblk ? b1[c] : 0.0f;
#pragma unroll
        for (int i = 0; i < 4; i++) {
            int mrow = m0 + wr + i * 16 + lv;
#pragma unroll
            for (int e = 0; e < 4; e++)
                dst[(size_t)(mrow + e) * K3 + c] = f2h(acc[i][j][e] + bias);
        }
    }
}

// ---------- main pair kernel: 32x32x16 f16 ----------
// 128 thr (2 waves). Wave w owns i = i0+2w, i0+2w+1 (q=2) x 32 j.
// Per K-64 iter: 4 k16-slices; per slice form A (relu(head_i+tail_j)), read
// 3 og W2 frags from LDS ring; 24 MFMAs/wave-iter.
__device__ __forceinline__ f16x8 form8h(uint4 hq, uint4 tq) {
    union { uint4 q; f16x8 v; } H, T;
    H.q = hq; T.q = tq;
    f16x8 s = H.v + T.v;
    const f16x8 z = {0, 0, 0, 0, 0, 0, 0, 0};
    return __builtin_elementwise_max(s, z);
}

__global__ __launch_bounds__(128) void k_pair(
        const unsigned short* __restrict__ headh,  // [512][2304] f16
        const unsigned short* __restrict__ tailh,  // [512][2304] f16
        const unsigned short* __restrict__ w2f,    // [144][3][64][8] f16 frag order
        const float* __restrict__ b2,              // [96]
        float* __restrict__ out) {                 // [4][128][128][96] fp32
    // 4-deep ring of K-step-64 W2 buffers: 4 x 12KB = 48KB
    __shared__ __align__(16) unsigned short lds[4][6144];

    const int tid = threadIdx.x;
    const int w = tid >> 6, l = tid & 63;
    const int lo = l & 31;          // o (and j) sub-index
    const int ko = (l >> 5) * 8;    // k half-slice offset
    const int jb = blockIdx.x;      // 0..3   (32-j groups)
    const int ig = blockIdx.y;      // 0..31  (4-i groups)
    const int b  = blockIdx.z;      // 0..3
    const int i0 = ig * 4 + w * 2;

    const unsigned short* Hp = headh + (size_t)(b * S_ + i0) * K3;           // rows i0, i0+1
    const unsigned short* Tp = tailh + (size_t)(b * S_ + jb * 32 + lo) * K3; // per-lane j row

    f32x16 acc[2][3] = {};
    float b2v[3];
#pragma unroll
    for (int og = 0; og < 3; og++) b2v[og] = b2[og * 32 + lo];

    // stage K-step n (12KB) into ring buffer sbuf: 6 x 16B per thread
    auto stage = [&](int sbuf, int n) {
        const unsigned short* src = w2f + (size_t)n * 6144;
#pragma unroll
        for (int i = 0; i < 6; ++i)
            gload_lds16(src + i * 1024 + tid * 8, &lds[sbuf][i * 1024 + tid * 8]);
    };

    // h/t registers for iter 0: 4 slices x (tail + 2 head) = 12 uint4
    uint4 t8[4], ha[4], hb[4];
#pragma unroll
    for (int si = 0; si < 4; si++) {
        t8[si] = *(const uint4*)(Tp + si * 16 + ko);
        ha[si] = *(const uint4*)(Hp + si * 16 + ko);
        hb[si] = *(const uint4*)(Hp + K3 + si * 16 + ko);
    }

    stage(0, 0);
    stage(1, 1);

    for (int n = 0; n < NIT; ++n) {
        // uniform depth-2 W2 staging (dummy re-stage in tail iters keeps counts exact)
        stage((n + 2) & 3, (n + 2 < NIT) ? (n + 2) : (NIT - 1));
        // depth-1 h/t register prefetch (12 loads; clamped on last iter)
        const int kn = ((n < NIT - 1) ? (n + 1) : n) * 64;
        uint4 t8n[4], han[4], hbn[4];
#pragma unroll
        for (int si = 0; si < 4; si++) {
            t8n[si] = *(const uint4*)(Tp + kn + si * 16 + ko);
            han[si] = *(const uint4*)(Hp + kn + si * 16 + ko);
            hbn[si] = *(const uint4*)(Hp + K3 + kn + si * 16 + ko);
        }

        // counted wait: younger-than-ht(n) = stage(n+2)[6] + ht(n+1)[12] = 18.
        // Retires ht(n) and stage(n..n+1); keeps next stage + next ht in flight.
        asm volatile("s_waitcnt vmcnt(18)" ::: "memory");
        __builtin_amdgcn_s_barrier();

        const unsigned short* Lb = &lds[n & 3][0];
#pragma unroll
        for (int si = 0; si < 4; si++) {
            f16x8 a0 = form8h(ha[si], t8[si]);
            f16x8 a1 = form8h(hb[si], t8[si]);
#pragma unroll
            for (int og = 0; og < 3; og++) {
                f16x8 bfr = *(const f16x8*)(Lb + (si * 3 + og) * 512 + l * 8);
                acc[0][og] = __builtin_amdgcn_mfma_f32_32x32x16_f16(a0, bfr, acc[0][og], 0, 0, 0);
                acc[1][og] = __builtin_amdgcn_mfma_f32_32x32x16_f16(a1, bfr, acc[1][og], 0, 0, 0);
            }
        }
#pragma unroll
        for (int si = 0; si < 4; si++) { t8[si] = t8n[si]; ha[si] = han[si]; hb[si] = hbn[si]; }
    }

    // C/D layout (32x32): col o = og*32 + (l&31); row j = (r&3) + 8*(r>>2) + 4*(l>>5)
#pragma unroll
    for (int q = 0; q < 2; q++) {
        float* O = out + ((size_t)(b * S_ + i0 + q) * S_ + jb * 32) * NOUT + lo;
#pragma unroll
        for (int og = 0; og < 3; og++)
#pragma unroll
            for (int r = 0; r < 16; r++) {
                int j = (r & 3) + 8 * (r >> 2) + 4 * (l >> 5);
                O[(size_t)j * NOUT + og * 32] = acc[q][og][r] + b2v[og];
            }
    }
}

extern "C" void kernel_launch(void* const* d_in, const int* in_sizes, int n_in,
                              void* d_out, int out_size, void* d_ws, size_t ws_size,
                              hipStream_t stream) {
    const float* x  = (const float*)d_in[0];   // [4][128][768]
    const float* W1 = (const float*)d_in[1];   // [1536][2304]
    const float* b1 = (const float*)d_in[2];   // [2304]
    const float* W2 = (const float*)d_in[3];   // [2304][96]
    const float* b2 = (const float*)d_in[4];   // [96]
    float* out = (float*)d_out;

    char* ws = (char*)d_ws;
    unsigned short* xb    = (unsigned short*)(ws);              //  512*768   bf16
    unsigned short* w2f   = (unsigned short*)(ws);              //  144*3*64*8 f16 (overlays xb; written after gemm1)
    unsigned short* w1t   = (unsigned short*)(ws +   786432);   // 4608*768   bf16
    unsigned short* headh = (unsigned short*)(ws +  8306688);   //  512*2304  f16
    unsigned short* tailh = (unsigned short*)(ws + 10665984);   //  512*2304  f16
    // total ws use: 13,025,280 bytes

    hipLaunchKernelGGL(k_cvt_x, dim3(384), dim3(256), 0, stream,
                       (const float4*)x, (ushort4*)xb);
    hipLaunchKernelGGL(k_transpose, dim3(72, 24, 2), dim3(256), 0, stream,
                       W1, w1t, H_, K3, (long)H_ * K3, (long)K3 * H_);
    hipLaunchKernelGGL(k_gemm1, dim3(36, 4), dim3(256), 0, stream,
                       xb, w1t, b1, headh, tailh);
    // pack W2 frags AFTER gemm1 (w2f overlays xb, which gemm1 reads)
    hipLaunchKernelGGL(k_pack_w2, dim3(108), dim3(256), 0, stream,
                       W2, w2f);
    hipLaunchKernelGGL(k_pair, dim3(4, 32, 4), dim3(128), 0, stream,
                       headh, tailh, w2f, b2, out);
}

// Round 14
// 81.002 us; speedup vs baseline: 1.0753x; 1.0753x over previous
//
#include <hip/hip_runtime.h>
#include <hip/hip_bf16.h>

// Problem: B=4, S=128, H=768, OUT*TAG=96
// scores[b,i,j,o] = sum_k relu(head[b,i,k] + tail[b,j,k] + b1[k]) * W2[k,o] + b2[o]
// R13: R12 with the ring-2 WAR race fixed — stage(n+1) issued AFTER the barrier
//      (all waves' compute(n-1) LDS reads provably complete by then), vmcnt(6).
//      2-wave blocks, ring-2 LDS (24KB) -> 6 blocks/CU, 12 waves/CU, setprio MFMA.

typedef __bf16 bf16x8 __attribute__((ext_vector_type(8)));
typedef _Float16 f16x8 __attribute__((ext_vector_type(8)));
typedef float f32x4 __attribute__((ext_vector_type(4)));

#define S_   128
#define H_   768
#define K3   2304   // 3*H
#define NOUT 96
#define NIT  36     // K-step-64 iterations

__device__ __forceinline__ unsigned short f2bf(float f) {
    union { __bf16 b; unsigned short u; } c;
    c.b = (__bf16)f;   // RNE
    return c.u;
}

__device__ __forceinline__ unsigned short f2h(float f) {
    union { _Float16 h; unsigned short u; } c;
    c.h = (_Float16)f;
    return c.u;
}

__device__ __forceinline__ void gload_lds16(const unsigned short* g, unsigned short* l) {
    __builtin_amdgcn_global_load_lds(
        (const __attribute__((address_space(1))) void*)g,
        (__attribute__((address_space(3))) void*)l,
        16, 0, 0);
}

// ---------- prep: x fp32 -> bf16 (layout unchanged, [512][768]) ----------
__global__ void k_cvt_x(const float4* __restrict__ x, ushort4* __restrict__ xb) {
    int t = blockIdx.x * 256 + threadIdx.x;   // 98304 threads, exact
    float4 v = x[t];
    ushort4 o;
    o.x = f2bf(v.x); o.y = f2bf(v.y); o.z = f2bf(v.z); o.w = f2bf(v.w);
    xb[t] = o;
}

// ---------- prep: transpose fp32 [R][C] -> bf16 [C][R] (for W1) ----------
__global__ void k_transpose(const float* __restrict__ src, unsigned short* __restrict__ dst,
                            int R, int C, long srcZ, long dstZ) {
    src += (long)blockIdx.z * srcZ;
    dst += (long)blockIdx.z * dstZ;
    __shared__ float tile[32][33];
    int c0 = blockIdx.x * 32, r0 = blockIdx.y * 32;
    int row = threadIdx.x >> 3;          // 0..31
    int c4  = (threadIdx.x & 7) * 4;     // 0..28
    float4 v = *(const float4*)(src + (size_t)(r0 + row) * C + c0 + c4);
    tile[row][c4 + 0] = v.x; tile[row][c4 + 1] = v.y;
    tile[row][c4 + 2] = v.z; tile[row][c4 + 3] = v.w;
    __syncthreads();
    ushort4 o;
    o.x = f2bf(tile[c4 + 0][row]); o.y = f2bf(tile[c4 + 1][row]);
    o.z = f2bf(tile[c4 + 2][row]); o.w = f2bf(tile[c4 + 3][row]);
    *(ushort4*)(dst + (size_t)(c0 + row) * R + r0 + c4) = o;
}

// ---------- prep: pack W2 f32 [2304][96] -> f16 fragment order [72][6][64][8] ----------
// frag elem(kc,f,l,e) = W2[kc*32 + (l>>4)*8 + e][f*16 + (l&15)]  as f16
__global__ void k_pack_w2(const float* __restrict__ W2,
                          unsigned short* __restrict__ w2f) {
    int t = blockIdx.x * 256 + threadIdx.x;   // 27648 threads exact (108 blocks)
    int l = t & 63, f = (t >> 6) % 6, kc = t / 384;
    int k0 = kc * 32 + (l >> 4) * 8;
    int o  = f * 16 + (l & 15);
    unsigned short v[8];
#pragma unroll
    for (int e = 0; e < 8; e++)
        v[e] = f2h(W2[(size_t)(k0 + e) * NOUT + o]);
    *(uint4*)(w2f + (size_t)t * 8) = *(const uint4*)v;
}

// ---------- GEMM1: 64x128 tiles (288 blocks), bf16 MFMA, f16 outputs ----------
__global__ __launch_bounds__(256) void k_gemm1(
        const unsigned short* __restrict__ xb,     // [512][768] bf16
        const unsigned short* __restrict__ w1t,    // [4608][768] bf16
        const float* __restrict__ b1,              // [2304]
        unsigned short* __restrict__ headh,        // [512][2304] f16
        unsigned short* __restrict__ tailh) {      // [512][2304] f16
    __shared__ unsigned short As[64 * 32];
    __shared__ unsigned short Bs[128 * 32];
    const int tid = threadIdx.x;
    const int l = tid & 63, w = tid >> 6;
    const int m0 = blockIdx.y * 64;
    const int n0 = blockIdx.x * 128;
    const int wr = (w >> 1) * 32, wc = (w & 1) * 64;
    const int lr = l & 15, lk = (l >> 4) * 8;
    f32x4 acc[2][4] = {};

    for (int kt = 0; kt < H_; kt += 32) {
        {   // A: 64x32 = 2048 elems, 1 x 16B per thread
            int row = tid >> 2, seg = (tid & 3) * 8;
            gload_lds16(xb + (size_t)(m0 + row) * H_ + kt + seg, As + tid * 8);
        }
#pragma unroll
        for (int p = 0; p < 2; ++p) {   // B: 128x32 = 4096 elems, 2 x 16B per thread
            int idx = p * 256 + tid;
            int row = idx >> 2, seg = (idx & 3) * 8;
            gload_lds16(w1t + (size_t)(n0 + row) * H_ + kt + seg, Bs + idx * 8);
        }
        asm volatile("s_waitcnt vmcnt(0)" ::: "memory");
        __syncthreads();
        bf16x8 af[2], bfr[4];
#pragma unroll
        for (int i = 0; i < 2; i++) af[i]  = *(const bf16x8*)(As + (wr + i * 16 + lr) * 32 + lk);
#pragma unroll
        for (int j = 0; j < 4; j++) bfr[j] = *(const bf16x8*)(Bs + (wc + j * 16 + lr) * 32 + lk);
#pragma unroll
        for (int i = 0; i < 2; i++)
#pragma unroll
            for (int j = 0; j < 4; j++)
                acc[i][j] = __builtin_amdgcn_mfma_f32_16x16x32_bf16(af[i], bfr[j], acc[i][j], 0, 0, 0);
        __syncthreads();
    }

    const bool tailblk = (n0 >= K3);
    unsigned short* dst = tailblk ? tailh : headh;
    const int nloc = n0 - (tailblk ? K3 : 0);
    const int lv = (l >> 4) * 4;
#pragma unroll
    for (int j = 0; j < 4; j++) {
        int c = nloc + wc + j * 16 + lr;
        float bias = tailblk ? b1[c] : 0.0f;
#pragma unroll
        for (int i = 0; i < 2; i++) {
            int mrow = m0 + wr + i * 16 + lv;
#pragma unroll
            for (int e = 0; e < 4; e++)
                dst[(size_t)(mrow + e) * K3 + c] = f2h(acc[i][j][e] + bias);
        }
    }
}

// ---------- main pair kernel (f16, 2-wave blocks, ring-2, 6 blocks/CU) ----------
// 128 thr (2 waves), tile 4i x 16j; wave w owns i = i0+2w, i0+2w+1.
// Per iter n: ht(n+1) prefetch [6] -> vmcnt(6) (retires ht(n)+stage(n), keeps
// ht(n+1)) -> s_barrier -> stage(n+1) [6, safe: all compute(n-1) LDS reads done
// before any wave passed barrier(n)] -> setprio(1) form+24 MFMA setprio(0).
__device__ __forceinline__ f16x8 form8h(uint4 hq, uint4 tq) {
    union { uint4 q; f16x8 v; } H, T;
    H.q = hq; T.q = tq;
    f16x8 s = H.v + T.v;
    const f16x8 z = {0, 0, 0, 0, 0, 0, 0, 0};
    return __builtin_elementwise_max(s, z);
}

__global__ __launch_bounds__(128) void k_pair(
        const unsigned short* __restrict__ headh,  // [512][2304] f16
        const unsigned short* __restrict__ tailh,  // [512][2304] f16
        const unsigned short* __restrict__ w2f,    // [72][6][64][8] f16 frag order
        const float* __restrict__ b2,              // [96]
        float* __restrict__ out) {                 // [4][128][128][96] fp32
    // ring-2 of K-step-64 W2 buffers: 2 x 12KB = 24KB -> 6 blocks/CU
    __shared__ __align__(16) unsigned short lds[2][6144];

    const int tid = threadIdx.x;
    const int w = tid >> 6, l = tid & 63;
    const int lr = l & 15, lkq = l >> 4;
    const int lkoff = lkq * 8;
    const int jb = blockIdx.x;     // 0..7
    const int ig = blockIdx.y;     // 0..31  (4-i groups)
    const int b  = blockIdx.z;     // 0..3
    const int i0 = ig * 4;

    const unsigned short* Hp = headh + (size_t)(b * S_ + i0 + 2 * w) * K3;
    const unsigned short* Tp = tailh + (size_t)(b * S_ + jb * 16 + lr) * K3;

    f32x4 acc[2][6] = {};
    float b2v[6];
#pragma unroll
    for (int f = 0; f < 6; f++) b2v[f] = b2[f * 16 + lr];

    // stage K-step n (12KB) into buffer sbuf: 6 x 16B per thread (128 thr)
    auto stage = [&](int sbuf, int n) {
        const unsigned short* src = w2f + (size_t)n * 6144;
#pragma unroll
        for (int i = 0; i < 6; ++i)
            gload_lds16(src + i * 1024 + tid * 8, &lds[sbuf][i * 1024 + tid * 8]);
    };

    stage(0, 0);
    // ht(0): 6 loads
    uint4 t8[2], ha[2], hb[2];
#pragma unroll
    for (int kk = 0; kk < 2; kk++) {
        t8[kk] = *(const uint4*)(Tp + kk * 32 + lkoff);
        ha[kk] = *(const uint4*)(Hp + kk * 32 + lkoff);
        hb[kk] = *(const uint4*)(Hp + K3 + kk * 32 + lkoff);
    }

    for (int n = 0; n < NIT; ++n) {
        // ht(n+1) register prefetch (6 loads; clamped on last iter)
        const int kn = ((n < NIT - 1) ? (n + 1) : n) * 64;
        uint4 t8n[2], han[2], hbn[2];
#pragma unroll
        for (int kk = 0; kk < 2; kk++) {
            t8n[kk] = *(const uint4*)(Tp + kn + kk * 32 + lkoff);
            han[kk] = *(const uint4*)(Hp + kn + kk * 32 + lkoff);
            hbn[kk] = *(const uint4*)(Hp + K3 + kn + kk * 32 + lkoff);
        }

        // counted wait: outstanding = ht(n)[6, oldest] + stage(n)[6] + ht(n+1)[6, newest].
        // vmcnt(6) retires ht(n)+stage(n); keeps ht(n+1) in flight.
        asm volatile("s_waitcnt vmcnt(6)" ::: "memory");
        __builtin_amdgcn_s_barrier();

        // stage(n+1) AFTER the barrier: buf (n+1)&1's readers (compute(n-1)) all
        // completed their ds_reads before reaching barrier(n). Clamped dummy on
        // the last iter keeps vmcnt counts uniform.
        stage((n + 1) & 1, (n + 1 < NIT) ? (n + 1) : (NIT - 1));

        const unsigned short* Lb = &lds[n & 1][0];
        __builtin_amdgcn_s_setprio(1);
#pragma unroll
        for (int kk = 0; kk < 2; kk++) {
            f16x8 a0 = form8h(ha[kk], t8[kk]);
            f16x8 a1 = form8h(hb[kk], t8[kk]);
#pragma unroll
            for (int f = 0; f < 6; f++) {
                f16x8 bfr = *(const f16x8*)(Lb + kk * 3072 + f * 512 + l * 8);
                acc[0][f] = __builtin_amdgcn_mfma_f32_16x16x32_f16(a0, bfr, acc[0][f], 0, 0, 0);
                acc[1][f] = __builtin_amdgcn_mfma_f32_16x16x32_f16(a1, bfr, acc[1][f], 0, 0, 0);
            }
        }
        __builtin_amdgcn_s_setprio(0);
#pragma unroll
        for (int kk = 0; kk < 2; kk++) { t8[kk] = t8n[kk]; ha[kk] = han[kk]; hb[kk] = hbn[kk]; }
    }

    float* O = out + (((size_t)(b * S_ + i0 + 2 * w)) * S_ + jb * 16) * NOUT;
#pragma unroll
    for (int q = 0; q < 2; q++)
#pragma unroll
        for (int f = 0; f < 6; f++)
#pragma unroll
            for (int e = 0; e < 4; e++) {
                int j = lkq * 4 + e;
                O[(size_t)q * S_ * NOUT + (size_t)j * NOUT + f * 16 + lr] = acc[q][f][e] + b2v[f];
            }
}

extern "C" void kernel_launch(void* const* d_in, const int* in_sizes, int n_in,
                              void* d_out, int out_size, void* d_ws, size_t ws_size,
                              hipStream_t stream) {
    const float* x  = (const float*)d_in[0];   // [4][128][768]
    const float* W1 = (const float*)d_in[1];   // [1536][2304]
    const float* b1 = (const float*)d_in[2];   // [2304]
    const float* W2 = (const float*)d_in[3];   // [2304][96]
    const float* b2 = (const float*)d_in[4];   // [96]
    float* out = (float*)d_out;

    char* ws = (char*)d_ws;
    unsigned short* xb    = (unsigned short*)(ws);              //  512*768   bf16
    unsigned short* w2f   = (unsigned short*)(ws);              //  72*6*64*8 f16 (overlays xb; written after gemm1)
    unsigned short* w1t   = (unsigned short*)(ws +   786432);   // 4608*768   bf16
    unsigned short* headh = (unsigned short*)(ws +  8306688);   //  512*2304  f16
    unsigned short* tailh = (unsigned short*)(ws + 10665984);   //  512*2304  f16
    // total ws use: 13,025,280 bytes

    hipLaunchKernelGGL(k_cvt_x, dim3(384), dim3(256), 0, stream,
                       (const float4*)x, (ushort4*)xb);
    hipLaunchKernelGGL(k_transpose, dim3(72, 24, 2), dim3(256), 0, stream,
                       W1, w1t, H_, K3, (long)H_ * K3, (long)K3 * H_);
    hipLaunchKernelGGL(k_gemm1, dim3(36, 8), dim3(256), 0, stream,
                       xb, w1t, b1, headh, tailh);
    // pack W2 frags AFTER gemm1 (w2f overlays xb, which gemm1 reads)
    hipLaunchKernelGGL(k_pack_w2, dim3(108), dim3(256), 0, stream,
                       W2, w2f);
    hipLaunchKernelGGL(k_pair, dim3(8, 32, 4), dim3(128), 0, stream,
                       headh, tailh, w2f, b2, out);
}

// Round 15
// 74.564 us; speedup vs baseline: 1.1681x; 1.0863x over previous
//
#include <hip/hip_runtime.h>
#include <hip/hip_bf16.h>

// Problem: B=4, S=128, H=768, OUT*TAG=96
// scores[b,i,j,o] = sum_k relu(head[b,i,k] + tail[b,j,k] + b1[k]) * W2[k,o] + b2[o]
// R14: (a) k_pair = 2-wave blocks (4i x 16j), ring-3 LDS (36KB -> 4 blocks/CU,
//      8 waves/CU, 4 barrier domains), depth-2 stage(n+2)-after-barrier, vmcnt(12).
//      (b) all prep (cvt_x, W1-transpose, pack_w2) fused into one dispatch.

typedef __bf16 bf16x8 __attribute__((ext_vector_type(8)));
typedef _Float16 f16x8 __attribute__((ext_vector_type(8)));
typedef float f32x4 __attribute__((ext_vector_type(4)));

#define S_   128
#define H_   768
#define K3   2304   // 3*H
#define NOUT 96
#define NIT  36     // K-step-64 iterations

__device__ __forceinline__ unsigned short f2bf(float f) {
    union { __bf16 b; unsigned short u; } c;
    c.b = (__bf16)f;   // RNE
    return c.u;
}

__device__ __forceinline__ unsigned short f2h(float f) {
    union { _Float16 h; unsigned short u; } c;
    c.h = (_Float16)f;
    return c.u;
}

__device__ __forceinline__ void gload_lds16(const unsigned short* g, unsigned short* l) {
    __builtin_amdgcn_global_load_lds(
        (const __attribute__((address_space(1))) void*)g,
        (__attribute__((address_space(3))) void*)l,
        16, 0, 0);
}

// ---------- fused prep: cvt_x | transpose W1 | pack W2 (role by blockIdx.x) ----------
// blocks [0,384):    xb[t] = bf16(x[t]) vectorized x4
// blocks [384,3840): W1 fp32 [1536][2304] -> w1t bf16 [4608][768] (32x32 LDS tiles)
// blocks [3840,3948): W2 fp32 [2304][96] -> w2f f16 frag order [72][6][64][8]
__global__ __launch_bounds__(256) void k_prep(
        const float* __restrict__ x, unsigned short* __restrict__ xb,
        const float* __restrict__ W1, unsigned short* __restrict__ w1t,
        const float* __restrict__ W2, unsigned short* __restrict__ w2f) {
    __shared__ float tile[32][33];
    const int bid = blockIdx.x, tid = threadIdx.x;
    if (bid < 384) {
        int t = bid * 256 + tid;
        float4 v = ((const float4*)x)[t];
        ushort4 o;
        o.x = f2bf(v.x); o.y = f2bf(v.y); o.z = f2bf(v.z); o.w = f2bf(v.w);
        ((ushort4*)xb)[t] = o;
    } else if (bid < 3840) {
        // transpose [1536][2304] -> [4608][768]: treat as 2 halves of [768][2304]
        int idx = bid - 384;
        int bx = idx % 72, by = (idx / 72) % 24, bz = idx / 1728;   // 72 x 24 x 2
        const float* src = W1 + (size_t)bz * H_ * K3;
        unsigned short* dst = w1t + (size_t)bz * K3 * H_;
        int c0 = bx * 32, r0 = by * 32;
        int row = tid >> 3, c4 = (tid & 7) * 4;
        float4 v = *(const float4*)(src + (size_t)(r0 + row) * K3 + c0 + c4);
        tile[row][c4 + 0] = v.x; tile[row][c4 + 1] = v.y;
        tile[row][c4 + 2] = v.z; tile[row][c4 + 3] = v.w;
        __syncthreads();
        ushort4 o;
        o.x = f2bf(tile[c4 + 0][row]); o.y = f2bf(tile[c4 + 1][row]);
        o.z = f2bf(tile[c4 + 2][row]); o.w = f2bf(tile[c4 + 3][row]);
        *(ushort4*)(dst + (size_t)(c0 + row) * H_ + r0 + c4) = o;
    } else {
        int t = (bid - 3840) * 256 + tid;   // 27648 exact
        int l = t & 63, f = (t >> 6) % 6, kc = t / 384;
        int k0 = kc * 32 + (l >> 4) * 8;
        int o  = f * 16 + (l & 15);
        unsigned short v[8];
#pragma unroll
        for (int e = 0; e < 8; e++)
            v[e] = f2h(W2[(size_t)(k0 + e) * NOUT + o]);
        *(uint4*)(w2f + (size_t)t * 8) = *(const uint4*)v;
    }
}

// ---------- GEMM1: 64x128 tiles (288 blocks), bf16 MFMA, f16 outputs (R13-verified) ----------
__global__ __launch_bounds__(256) void k_gemm1(
        const unsigned short* __restrict__ xb,     // [512][768] bf16
        const unsigned short* __restrict__ w1t,    // [4608][768] bf16
        const float* __restrict__ b1,              // [2304]
        unsigned short* __restrict__ headh,        // [512][2304] f16
        unsigned short* __restrict__ tailh) {      // [512][2304] f16
    __shared__ unsigned short As[64 * 32];
    __shared__ unsigned short Bs[128 * 32];
    const int tid = threadIdx.x;
    const int l = tid & 63, w = tid >> 6;
    const int m0 = blockIdx.y * 64;
    const int n0 = blockIdx.x * 128;
    const int wr = (w >> 1) * 32, wc = (w & 1) * 64;
    const int lr = l & 15, lk = (l >> 4) * 8;
    f32x4 acc[2][4] = {};

    for (int kt = 0; kt < H_; kt += 32) {
        {
            int row = tid >> 2, seg = (tid & 3) * 8;
            gload_lds16(xb + (size_t)(m0 + row) * H_ + kt + seg, As + tid * 8);
        }
#pragma unroll
        for (int p = 0; p < 2; ++p) {
            int idx = p * 256 + tid;
            int row = idx >> 2, seg = (idx & 3) * 8;
            gload_lds16(w1t + (size_t)(n0 + row) * H_ + kt + seg, Bs + idx * 8);
        }
        asm volatile("s_waitcnt vmcnt(0)" ::: "memory");
        __syncthreads();
        bf16x8 af[2], bfr[4];
#pragma unroll
        for (int i = 0; i < 2; i++) af[i]  = *(const bf16x8*)(As + (wr + i * 16 + lr) * 32 + lk);
#pragma unroll
        for (int j = 0; j < 4; j++) bfr[j] = *(const bf16x8*)(Bs + (wc + j * 16 + lr) * 32 + lk);
#pragma unroll
        for (int i = 0; i < 2; i++)
#pragma unroll
            for (int j = 0; j < 4; j++)
                acc[i][j] = __builtin_amdgcn_mfma_f32_16x16x32_bf16(af[i], bfr[j], acc[i][j], 0, 0, 0);
        __syncthreads();
    }

    const bool tailblk = (n0 >= K3);
    unsigned short* dst = tailblk ? tailh : headh;
    const int nloc = n0 - (tailblk ? K3 : 0);
    const int lv = (l >> 4) * 4;
#pragma unroll
    for (int j = 0; j < 4; j++) {
        int c = nloc + wc + j * 16 + lr;
        float bias = tailblk ? b1[c] : 0.0f;
#pragma unroll
        for (int i = 0; i < 2; i++) {
            int mrow = m0 + wr + i * 16 + lv;
#pragma unroll
            for (int e = 0; e < 4; e++)
                dst[(size_t)(mrow + e) * K3 + c] = f2h(acc[i][j][e] + bias);
        }
    }
}

// ---------- main pair kernel ----------
// 128 thr (2 waves), tile 4i x 16j; wave w owns i = i0+2w, i0+2w+1.
// Ring-3 x 12KB (36KB) -> 4 blocks/CU, 8 waves/CU, 4 barrier domains.
// Iter n: ht(n+1) [6] -> vmcnt(12) (12 youngest = stage(n+1)+ht(n+1); stage(n)
// provably landed; ht deps compiler-tracked) -> s_barrier -> stage(n+2) [6,
// WAR-safe: buf (n+2)%3 readers finished before barrier(n)] -> setprio MFMA.
__device__ __forceinline__ f16x8 form8h(uint4 hq, uint4 tq) {
    union { uint4 q; f16x8 v; } H, T;
    H.q = hq; T.q = tq;
    f16x8 s = H.v + T.v;
    const f16x8 z = {0, 0, 0, 0, 0, 0, 0, 0};
    return __builtin_elementwise_max(s, z);
}

__global__ __launch_bounds__(128) void k_pair(
        const unsigned short* __restrict__ headh,  // [512][2304] f16
        const unsigned short* __restrict__ tailh,  // [512][2304] f16
        const unsigned short* __restrict__ w2f,    // [72][6][64][8] f16 frag order
        const float* __restrict__ b2,              // [96]
        float* __restrict__ out) {                 // [4][128][128][96] fp32
    __shared__ __align__(16) unsigned short lds[3][6144];   // ring-3, 36KB

    const int tid = threadIdx.x;
    const int w = tid >> 6, l = tid & 63;
    const int lr = l & 15, lkq = l >> 4;
    const int lkoff = lkq * 8;
    const int jb = blockIdx.x;     // 0..7
    const int ig = blockIdx.y;     // 0..31  (4-i groups)
    const int b  = blockIdx.z;     // 0..3
    const int i0 = ig * 4;

    const unsigned short* Hp = headh + (size_t)(b * S_ + i0 + 2 * w) * K3;
    const unsigned short* Tp = tailh + (size_t)(b * S_ + jb * 16 + lr) * K3;

    f32x4 acc[2][6] = {};
    float b2v[6];
#pragma unroll
    for (int f = 0; f < 6; f++) b2v[f] = b2[f * 16 + lr];

    // stage K-step n (12KB) into ring buffer sbuf: 6 x 16B per thread (128 thr)
    auto stage = [&](int sbuf, int n) {
        const unsigned short* src = w2f + (size_t)n * 6144;
#pragma unroll
        for (int i = 0; i < 6; ++i)
            gload_lds16(src + i * 1024 + tid * 8, &lds[sbuf][i * 1024 + tid * 8]);
    };

    stage(0, 0);
    stage(1, 1);
    // ht(0): 6 loads
    uint4 t8[2], ha[2], hb[2];
#pragma unroll
    for (int kk = 0; kk < 2; kk++) {
        t8[kk] = *(const uint4*)(Tp + kk * 32 + lkoff);
        ha[kk] = *(const uint4*)(Hp + kk * 32 + lkoff);
        hb[kk] = *(const uint4*)(Hp + K3 + kk * 32 + lkoff);
    }

    for (int n = 0; n < NIT; ++n) {
        // ht(n+1) register prefetch (6 loads; clamped on last iter)
        const int kn = ((n < NIT - 1) ? (n + 1) : n) * 64;
        uint4 t8n[2], han[2], hbn[2];
#pragma unroll
        for (int kk = 0; kk < 2; kk++) {
            t8n[kk] = *(const uint4*)(Tp + kn + kk * 32 + lkoff);
            han[kk] = *(const uint4*)(Hp + kn + kk * 32 + lkoff);
            hbn[kk] = *(const uint4*)(Hp + K3 + kn + kk * 32 + lkoff);
        }

        // 12 youngest vmem ops = stage(n+1)[6] + ht(n+1)[6] -> stage(n) landed.
        asm volatile("s_waitcnt vmcnt(12)" ::: "memory");
        __builtin_amdgcn_s_barrier();

        // depth-2 staging after barrier (clamped dummy keeps counts uniform)
        stage((n + 2) % 3, (n + 2 < NIT) ? (n + 2) : (NIT - 1));

        const unsigned short* Lb = &lds[n % 3][0];
        __builtin_amdgcn_s_setprio(1);
#pragma unroll
        for (int kk = 0; kk < 2; kk++) {
            f16x8 a0 = form8h(ha[kk], t8[kk]);
            f16x8 a1 = form8h(hb[kk], t8[kk]);
#pragma unroll
            for (int f = 0; f < 6; f++) {
                f16x8 bfr = *(const f16x8*)(Lb + kk * 3072 + f * 512 + l * 8);
                acc[0][f] = __builtin_amdgcn_mfma_f32_16x16x32_f16(a0, bfr, acc[0][f], 0, 0, 0);
                acc[1][f] = __builtin_amdgcn_mfma_f32_16x16x32_f16(a1, bfr, acc[1][f], 0, 0, 0);
            }
        }
        __builtin_amdgcn_s_setprio(0);
#pragma unroll
        for (int kk = 0; kk < 2; kk++) { t8[kk] = t8n[kk]; ha[kk] = han[kk]; hb[kk] = hbn[kk]; }
    }

    float* O = out + (((size_t)(b * S_ + i0 + 2 * w)) * S_ + jb * 16) * NOUT;
#pragma unroll
    for (int q = 0; q < 2; q++)
#pragma unroll
        for (int f = 0; f < 6; f++)
#pragma unroll
            for (int e = 0; e < 4; e++) {
                int j = lkq * 4 + e;
                O[(size_t)q * S_ * NOUT + (size_t)j * NOUT + f * 16 + lr] = acc[q][f][e] + b2v[f];
            }
}

extern "C" void kernel_launch(void* const* d_in, const int* in_sizes, int n_in,
                              void* d_out, int out_size, void* d_ws, size_t ws_size,
                              hipStream_t stream) {
    const float* x  = (const float*)d_in[0];   // [4][128][768]
    const float* W1 = (const float*)d_in[1];   // [1536][2304]
    const float* b1 = (const float*)d_in[2];   // [2304]
    const float* W2 = (const float*)d_in[3];   // [2304][96]
    const float* b2 = (const float*)d_in[4];   // [96]
    float* out = (float*)d_out;

    char* ws = (char*)d_ws;
    unsigned short* xb    = (unsigned short*)(ws);              //  512*768   bf16
    unsigned short* w1t   = (unsigned short*)(ws +   786432);   // 4608*768   bf16
    unsigned short* w2f   = (unsigned short*)(ws +  7864320);   //  72*6*64*8 f16 (442,368 B; ends at 8,306,688)
    unsigned short* headh = (unsigned short*)(ws +  8306688);   //  512*2304  f16
    unsigned short* tailh = (unsigned short*)(ws + 10665984);   //  512*2304  f16
    // total ws use: 13,025,280 bytes (unchanged footprint)

    hipLaunchKernelGGL(k_prep, dim3(3948), dim3(256), 0, stream,
                       x, xb, W1, w1t, W2, w2f);
    hipLaunchKernelGGL(k_gemm1, dim3(36, 8), dim3(256), 0, stream,
                       xb, w1t, b1, headh, tailh);
    hipLaunchKernelGGL(k_pair, dim3(8, 32, 4), dim3(128), 0, stream,
                       headh, tailh, w2f, b2, out);
}

// Round 16
// 67.571 us; speedup vs baseline: 1.2890x; 1.1035x over previous
//
#include <hip/hip_runtime.h>
#include <hip/hip_bf16.h>

// Problem: B=4, S=128, H=768, OUT*TAG=96
// scores[b,i,j,o] = sum_k relu(head[b,i,k] + tail[b,j,k] + b1[k]) * W2[k,o] + b2[o]
// R15: k_pair = pure-register dataflow. No LDS, no barriers. Wave = 2i x 32j
//      (W2 frag feeds 4 MFMAs), 1024 independent waves (1/SIMD), W2 streamed
//      from L2 with depth-1 register prefetch. MFMA-pipe-bound by construction.

typedef __bf16 bf16x8 __attribute__((ext_vector_type(8)));
typedef _Float16 f16x8 __attribute__((ext_vector_type(8)));
typedef float f32x4 __attribute__((ext_vector_type(4)));

#define S_   128
#define H_   768
#define K3   2304   // 3*H
#define NOUT 96
#define NIT  36     // K-step-64 iterations

__device__ __forceinline__ unsigned short f2bf(float f) {
    union { __bf16 b; unsigned short u; } c;
    c.b = (__bf16)f;   // RNE
    return c.u;
}

__device__ __forceinline__ unsigned short f2h(float f) {
    union { _Float16 h; unsigned short u; } c;
    c.h = (_Float16)f;
    return c.u;
}

__device__ __forceinline__ void gload_lds16(const unsigned short* g, unsigned short* l) {
    __builtin_amdgcn_global_load_lds(
        (const __attribute__((address_space(1))) void*)g,
        (__attribute__((address_space(3))) void*)l,
        16, 0, 0);
}

// ---------- fused prep: cvt_x | transpose W1 | pack W2 (role by blockIdx.x) ----------
__global__ __launch_bounds__(256) void k_prep(
        const float* __restrict__ x, unsigned short* __restrict__ xb,
        const float* __restrict__ W1, unsigned short* __restrict__ w1t,
        const float* __restrict__ W2, unsigned short* __restrict__ w2f) {
    __shared__ float tile[32][33];
    const int bid = blockIdx.x, tid = threadIdx.x;
    if (bid < 384) {
        int t = bid * 256 + tid;
        float4 v = ((const float4*)x)[t];
        ushort4 o;
        o.x = f2bf(v.x); o.y = f2bf(v.y); o.z = f2bf(v.z); o.w = f2bf(v.w);
        ((ushort4*)xb)[t] = o;
    } else if (bid < 3840) {
        int idx = bid - 384;
        int bx = idx % 72, by = (idx / 72) % 24, bz = idx / 1728;   // 72 x 24 x 2
        const float* src = W1 + (size_t)bz * H_ * K3;
        unsigned short* dst = w1t + (size_t)bz * K3 * H_;
        int c0 = bx * 32, r0 = by * 32;
        int row = tid >> 3, c4 = (tid & 7) * 4;
        float4 v = *(const float4*)(src + (size_t)(r0 + row) * K3 + c0 + c4);
        tile[row][c4 + 0] = v.x; tile[row][c4 + 1] = v.y;
        tile[row][c4 + 2] = v.z; tile[row][c4 + 3] = v.w;
        __syncthreads();
        ushort4 o;
        o.x = f2bf(tile[c4 + 0][row]); o.y = f2bf(tile[c4 + 1][row]);
        o.z = f2bf(tile[c4 + 2][row]); o.w = f2bf(tile[c4 + 3][row]);
        *(ushort4*)(dst + (size_t)(c0 + row) * H_ + r0 + c4) = o;
    } else {
        int t = (bid - 3840) * 256 + tid;   // 27648 exact
        int l = t & 63, f = (t >> 6) % 6, kc = t / 384;
        int k0 = kc * 32 + (l >> 4) * 8;
        int o  = f * 16 + (l & 15);
        unsigned short v[8];
#pragma unroll
        for (int e = 0; e < 8; e++)
            v[e] = f2h(W2[(size_t)(k0 + e) * NOUT + o]);
        *(uint4*)(w2f + (size_t)t * 8) = *(const uint4*)v;
    }
}

// ---------- GEMM1: 64x128 tiles (288 blocks), bf16 MFMA, f16 outputs ----------
__global__ __launch_bounds__(256) void k_gemm1(
        const unsigned short* __restrict__ xb,     // [512][768] bf16
        const unsigned short* __restrict__ w1t,    // [4608][768] bf16
        const float* __restrict__ b1,              // [2304]
        unsigned short* __restrict__ headh,        // [512][2304] f16
        unsigned short* __restrict__ tailh) {      // [512][2304] f16
    __shared__ unsigned short As[64 * 32];
    __shared__ unsigned short Bs[128 * 32];
    const int tid = threadIdx.x;
    const int l = tid & 63, w = tid >> 6;
    const int m0 = blockIdx.y * 64;
    const int n0 = blockIdx.x * 128;
    const int wr = (w >> 1) * 32, wc = (w & 1) * 64;
    const int lr = l & 15, lk = (l >> 4) * 8;
    f32x4 acc[2][4] = {};

    for (int kt = 0; kt < H_; kt += 32) {
        {
            int row = tid >> 2, seg = (tid & 3) * 8;
            gload_lds16(xb + (size_t)(m0 + row) * H_ + kt + seg, As + tid * 8);
        }
#pragma unroll
        for (int p = 0; p < 2; ++p) {
            int idx = p * 256 + tid;
            int row = idx >> 2, seg = (idx & 3) * 8;
            gload_lds16(w1t + (size_t)(n0 + row) * H_ + kt + seg, Bs + idx * 8);
        }
        asm volatile("s_waitcnt vmcnt(0)" ::: "memory");
        __syncthreads();
        bf16x8 af[2], bfr[4];
#pragma unroll
        for (int i = 0; i < 2; i++) af[i]  = *(const bf16x8*)(As + (wr + i * 16 + lr) * 32 + lk);
#pragma unroll
        for (int j = 0; j < 4; j++) bfr[j] = *(const bf16x8*)(Bs + (wc + j * 16 + lr) * 32 + lk);
#pragma unroll
        for (int i = 0; i < 2; i++)
#pragma unroll
            for (int j = 0; j < 4; j++)
                acc[i][j] = __builtin_amdgcn_mfma_f32_16x16x32_bf16(af[i], bfr[j], acc[i][j], 0, 0, 0);
        __syncthreads();
    }

    const bool tailblk = (n0 >= K3);
    unsigned short* dst = tailblk ? tailh : headh;
    const int nloc = n0 - (tailblk ? K3 : 0);
    const int lv = (l >> 4) * 4;
#pragma unroll
    for (int j = 0; j < 4; j++) {
        int c = nloc + wc + j * 16 + lr;
        float bias = tailblk ? b1[c] : 0.0f;
#pragma unroll
        for (int i = 0; i < 2; i++) {
            int mrow = m0 + wr + i * 16 + lv;
#pragma unroll
            for (int e = 0; e < 4; e++)
                dst[(size_t)(mrow + e) * K3 + c] = f2h(acc[i][j][e] + bias);
        }
    }
}

// ---------- main pair kernel: pure register dataflow ----------
// 256 thr = 4 INDEPENDENT waves (no LDS, no barriers). Wave: 2 i x 32 j.
// Per K-64 iter: 12 x b128 W2 stream loads (depth-1 prefetch), 8 ht loads
// (depth-1), 8 packed-f16 forms, 48 MFMAs (931 cyc/SIMD pipe — the pole).
__device__ __forceinline__ f16x8 form8h(uint4 hq, uint4 tq) {
    union { uint4 q; f16x8 v; } H, T;
    H.q = hq; T.q = tq;
    f16x8 s = H.v + T.v;
    const f16x8 z = {0, 0, 0, 0, 0, 0, 0, 0};
    return __builtin_elementwise_max(s, z);
}

__device__ __forceinline__ f16x8 u4f16(uint4 v) {
    union { uint4 q; f16x8 b; } c; c.q = v; return c.b;
}

__global__ __launch_bounds__(256, 1) void k_pair(
        const unsigned short* __restrict__ headh,  // [512][2304] f16
        const unsigned short* __restrict__ tailh,  // [512][2304] f16
        const unsigned short* __restrict__ w2f,    // [72][6][64][8] f16 frag order
        const float* __restrict__ b2,              // [96]
        float* __restrict__ out) {                 // [4][128][128][96] fp32
    const int tid = threadIdx.x;
    const int w = tid >> 6, l = tid & 63;
    const int lr = l & 15, lkq = l >> 4;
    const int lkoff = lkq * 8;
    const int jb = blockIdx.x;     // 0..3   (32-j groups)
    const int ig = blockIdx.y;     // 0..15  (8-i groups)
    const int b  = blockIdx.z;     // 0..3
    const int i0 = ig * 8 + w * 2;

    const unsigned short* Hp = headh + (size_t)(b * S_ + i0) * K3;              // rows i0, i0+1
    const unsigned short* T0 = tailh + (size_t)(b * S_ + jb * 32 + lr) * K3;    // j-group 0
    const unsigned short* T1 = T0 + (size_t)16 * K3;                            // j-group 1
    const unsigned short* Wp = w2f + l * 8;

    f32x4 acc[2][2][6] = {};   // [i][jg][f]
    float b2v[6];
#pragma unroll
    for (int f = 0; f < 6; f++) b2v[f] = b2[f * 16 + lr];

    // W2 cur/next register buffers: 12 x uint4 each (slot s = kk*6 + f)
    uint4 wcur[12], wnxt[12];
#pragma unroll
    for (int s = 0; s < 12; s++) wcur[s] = *(const uint4*)(Wp + s * 512);

    // ht cur: t[jg][kk], h[i][kk]
    uint4 tc[2][2], hc[2][2];
#pragma unroll
    for (int kk = 0; kk < 2; kk++) {
        tc[0][kk] = *(const uint4*)(T0 + kk * 32 + lkoff);
        tc[1][kk] = *(const uint4*)(T1 + kk * 32 + lkoff);
        hc[0][kk] = *(const uint4*)(Hp + kk * 32 + lkoff);
        hc[1][kk] = *(const uint4*)(Hp + K3 + kk * 32 + lkoff);
    }

    for (int n = 0; n < NIT; ++n) {
        // depth-1 prefetch of W2(n+1) (clamped dummy on last iter)
        const int np = (n + 1 < NIT) ? (n + 1) : (NIT - 1);
        const unsigned short* wsrc = Wp + (size_t)np * 6144;
#pragma unroll
        for (int s = 0; s < 12; s++) wnxt[s] = *(const uint4*)(wsrc + s * 512);
        // depth-1 prefetch of ht(n+1)
        const int kn = np * 64;
        uint4 tn[2][2], hn[2][2];
#pragma unroll
        for (int kk = 0; kk < 2; kk++) {
            tn[0][kk] = *(const uint4*)(T0 + kn + kk * 32 + lkoff);
            tn[1][kk] = *(const uint4*)(T1 + kn + kk * 32 + lkoff);
            hn[0][kk] = *(const uint4*)(Hp + kn + kk * 32 + lkoff);
            hn[1][kk] = *(const uint4*)(Hp + K3 + kn + kk * 32 + lkoff);
        }

        // compute on cur
#pragma unroll
        for (int kk = 0; kk < 2; kk++) {
            f16x8 a[2][2];   // [i][jg]
#pragma unroll
            for (int qi = 0; qi < 2; qi++)
#pragma unroll
                for (int jg = 0; jg < 2; jg++)
                    a[qi][jg] = form8h(hc[qi][kk], tc[jg][kk]);
#pragma unroll
            for (int f = 0; f < 6; f++) {
                f16x8 bfr = u4f16(wcur[kk * 6 + f]);
#pragma unroll
                for (int qi = 0; qi < 2; qi++)
#pragma unroll
                    for (int jg = 0; jg < 2; jg++)
                        acc[qi][jg][f] = __builtin_amdgcn_mfma_f32_16x16x32_f16(
                            a[qi][jg], bfr, acc[qi][jg][f], 0, 0, 0);
            }
        }

        // rotate buffers
#pragma unroll
        for (int s = 0; s < 12; s++) wcur[s] = wnxt[s];
#pragma unroll
        for (int kk = 0; kk < 2; kk++) {
            tc[0][kk] = tn[0][kk]; tc[1][kk] = tn[1][kk];
            hc[0][kk] = hn[0][kk]; hc[1][kk] = hn[1][kk];
        }
    }

    // epilogue: O[i0+qi][jb*32 + jg*16 + lkq*4 + e][f*16 + lr]
#pragma unroll
    for (int qi = 0; qi < 2; qi++) {
        float* O = out + ((size_t)(b * S_ + i0 + qi) * S_ + jb * 32) * NOUT;
#pragma unroll
        for (int jg = 0; jg < 2; jg++)
#pragma unroll
            for (int f = 0; f < 6; f++)
#pragma unroll
                for (int e = 0; e < 4; e++) {
                    int j = jg * 16 + lkq * 4 + e;
                    O[(size_t)j * NOUT + f * 16 + lr] = acc[qi][jg][f][e] + b2v[f];
                }
    }
}

extern "C" void kernel_launch(void* const* d_in, const int* in_sizes, int n_in,
                              void* d_out, int out_size, void* d_ws, size_t ws_size,
                              hipStream_t stream) {
    const float* x  = (const float*)d_in[0];   // [4][128][768]
    const float* W1 = (const float*)d_in[1];   // [1536][2304]
    const float* b1 = (const float*)d_in[2];   // [2304]
    const float* W2 = (const float*)d_in[3];   // [2304][96]
    const float* b2 = (const float*)d_in[4];   // [96]
    float* out = (float*)d_out;

    char* ws = (char*)d_ws;
    unsigned short* xb    = (unsigned short*)(ws);              //  512*768   bf16
    unsigned short* w1t   = (unsigned short*)(ws +   786432);   // 4608*768   bf16
    unsigned short* w2f   = (unsigned short*)(ws +  7864320);   //  72*6*64*8 f16
    unsigned short* headh = (unsigned short*)(ws +  8306688);   //  512*2304  f16
    unsigned short* tailh = (unsigned short*)(ws + 10665984);   //  512*2304  f16
    // total ws use: 13,025,280 bytes

    hipLaunchKernelGGL(k_prep, dim3(3948), dim3(256), 0, stream,
                       x, xb, W1, w1t, W2, w2f);
    hipLaunchKernelGGL(k_gemm1, dim3(36, 8), dim3(256), 0, stream,
                       xb, w1t, b1, headh, tailh);
    hipLaunchKernelGGL(k_pair, dim3(4, 16, 4), dim3(256), 0, stream,
                       headh, tailh, w2f, b2, out);
}